// Round 10
// baseline (140.921 us; speedup 1.0000x reference)
//
#include <hip/hip_runtime.h>
#include <hip/hip_bf16.h>
#include <stdint.h>

typedef __attribute__((ext_vector_type(8))) short short8;
typedef __attribute__((ext_vector_type(4))) float floatx4;

typedef const __attribute__((address_space(1))) void* gvp;
typedef __attribute__((address_space(3))) void* lvp;

__device__ __forceinline__ unsigned short f2bf(float f) {
    unsigned u = __float_as_uint(f);
    u += 0x7fffu + ((u >> 16) & 1u);   // RNE
    return (unsigned short)(u >> 16);
}

#define BAR()    do { asm volatile("" ::: "memory"); __builtin_amdgcn_s_barrier(); asm volatile("" ::: "memory"); } while (0)
#define WAITL()  do { asm volatile("s_waitcnt lgkmcnt(0)" ::: "memory"); __builtin_amdgcn_sched_barrier(0); } while (0)
#define WAITV12() asm volatile("s_waitcnt vmcnt(12)")
#define WAITV8()  asm volatile("s_waitcnt vmcnt(8)")
#define WAITV4()  asm volatile("s_waitcnt vmcnt(4)")
#define WAITV0()  asm volatile("s_waitcnt vmcnt(0)")

// ---------------- conversion: X, Wv straight; Wq, Wk transposed (for G) ----------------
__global__ __launch_bounds__(256)
void cvt_all(const float* __restrict__ x, const float* __restrict__ wq,
             const float* __restrict__ wk, const float* __restrict__ wv,
             unsigned short* __restrict__ Xb, unsigned short* __restrict__ WqT,
             unsigned short* __restrict__ WkT, unsigned short* __restrict__ Wvb) {
    const int b = blockIdx.x, t = threadIdx.x;
    if (b < 2304) {
        const float* in; unsigned short* out; long base;
        if (b < 2048) { in = x;  out = Xb;  base = (long)b * 1024; }
        else          { in = wv; out = Wvb; base = (long)(b - 2048) * 1024; }
        #pragma unroll
        for (int k = 0; k < 4; ++k) {
            long idx = base + k * 256 + t;
            float4 v = reinterpret_cast<const float4*>(in)[idx];
            uint2 o;
            o.x = (unsigned)f2bf(v.x) | ((unsigned)f2bf(v.y) << 16);
            o.y = (unsigned)f2bf(v.z) | ((unsigned)f2bf(v.w) << 16);
            reinterpret_cast<uint2*>(out)[idx] = o;
        }
    } else {
        const int bb = b - 2304;
        const float* in = (bb < 256) ? wq : wk;
        unsigned short* out = (bb < 256) ? WqT : WkT;
        const int tile = bb & 255;
        const int e0 = (tile >> 4) * 64, d0 = (tile & 15) * 64;
        __shared__ unsigned short ldsT[64][68];
        const int r = t >> 4, cq = t & 15;
        #pragma unroll
        for (int p = 0; p < 4; ++p) {
            const int e = p * 16 + r;
            float4 v = *reinterpret_cast<const float4*>(in + (long)(e0 + e) * 1024 + d0 + cq * 4);
            ldsT[cq*4+0][e] = f2bf(v.x);
            ldsT[cq*4+1][e] = f2bf(v.y);
            ldsT[cq*4+2][e] = f2bf(v.z);
            ldsT[cq*4+3][e] = f2bf(v.w);
        }
        __syncthreads();
        #pragma unroll
        for (int p = 0; p < 4; ++p) {
            const int d = p * 16 + r;
            ushort4 o = *reinterpret_cast<const ushort4*>(&ldsT[d][cq * 4]);
            *reinterpret_cast<ushort4*>(out + (long)(d0 + d) * 1024 + e0 + cq * 4) = o;
        }
    }
}

// ===================== 128x128 engine pieces (T2 swizzle) — G kernel =====================
__device__ __forceinline__ void stage_tile(unsigned short* Abuf, unsigned short* Bbuf,
                                           const unsigned short* A, int lda,
                                           const unsigned short* B, int ldb, int k0,
                                           int wid, int srow, int piece) {
    #pragma unroll
    for (int i = 0; i < 4; ++i) {
        const int c = wid * 4 + i;
        const int row = c * 8 + srow;
        const int cs = (piece * 16) ^ ((row & 7) << 4);
        __builtin_amdgcn_global_load_lds(
            (gvp)(reinterpret_cast<const char*>(A + (long)row * lda + k0) + cs),
            (lvp)(reinterpret_cast<char*>(Abuf) + c * 1024), 16, 0, 0);
        __builtin_amdgcn_global_load_lds(
            (gvp)(reinterpret_cast<const char*>(B + (long)row * ldb + k0) + cs),
            (lvp)(reinterpret_cast<char*>(Bbuf) + c * 1024), 16, 0, 0);
    }
}

__device__ __forceinline__ void compute_tile(floatx4 acc[4][4], const unsigned short* As,
                                             const unsigned short* Bs, int wm, int wn,
                                             int frow, int lane) {
    #pragma unroll
    for (int ks = 0; ks < 2; ++ks) {
        short8 af[4], bf[4];
        const int colb = ks * 64 + (lane >> 4) * 16;
        #pragma unroll
        for (int i = 0; i < 4; ++i) {
            const int ar = wm + i * 16 + frow;
            af[i] = *reinterpret_cast<const short8*>(
                reinterpret_cast<const char*>(As) + ar * 128 + (colb ^ ((ar & 7) << 4)));
            const int br = wn + i * 16 + frow;
            bf[i] = *reinterpret_cast<const short8*>(
                reinterpret_cast<const char*>(Bs) + br * 128 + (colb ^ ((br & 7) << 4)));
        }
        #pragma unroll
        for (int i = 0; i < 4; ++i)
            #pragma unroll
            for (int j = 0; j < 4; ++j)
                acc[i][j] = __builtin_amdgcn_mfma_f32_16x16x32_bf16(af[i], bf[j], acc[i][j], 0, 0, 0);
    }
}

// ---- G split-K chunk ----
__global__ __launch_bounds__(256, 2)
void g_chunk(const unsigned short* __restrict__ WkT, const unsigned short* __restrict__ WqT,
             float* __restrict__ Gw) {
    const int bx = blockIdx.x, by = blockIdx.y, bz = blockIdx.z;
    const unsigned short* A = WkT + (long)by * 128 * 1024;
    const unsigned short* B = WqT + (long)bx * 128 * 1024;

    __shared__ unsigned short As[2][128 * 64];
    __shared__ unsigned short Bs[2][128 * 64];

    const int tid = threadIdx.x, lane = tid & 63, wid = tid >> 6;
    const int srow = lane >> 3, piece = lane & 7;
    const int wm = (wid >> 1) * 64, wn = (wid & 1) * 64, frow = lane & 15;

    floatx4 acc[4][4] = {};
    const int kbase = bz * 256;

    stage_tile(As[0], Bs[0], A, 1024, B, 1024, kbase, wid, srow, piece);
    WAITV0(); BAR();
    int cur = 0;
    #pragma unroll 1
    for (int t = 0; t < 4; ++t) {
        if (t < 3)
            stage_tile(As[cur ^ 1], Bs[cur ^ 1], A, 1024, B, 1024, kbase + (t + 1) * 64,
                       wid, srow, piece);
        compute_tile(acc, As[cur], Bs[cur], wm, wn, frow, lane);
        WAITV0(); BAR();
        cur ^= 1;
    }

    float* Cb = Gw + (long)bz * (1 << 20) + (long)(by * 128) * 1024 + bx * 128;
    const int cr0 = wm + (lane >> 4) * 4;
    const int cc0 = wn + (lane & 15);
    #pragma unroll
    for (int i = 0; i < 4; ++i)
        #pragma unroll
        for (int j = 0; j < 4; ++j)
            #pragma unroll
            for (int r = 0; r < 4; ++r)
                Cb[(long)(cr0 + i * 16 + r) * 1024 + cc0 + j * 16] = acc[i][j][r];
}

// ---- reduce 4 G chunks -> bf16 G (scaled by 1/sqrt(1024)) ----
__global__ __launch_bounds__(256)
void reduce_g(const float* __restrict__ Gw, unsigned short* __restrict__ Gp) {
    const long i4 = (long)blockIdx.x * 256 + threadIdx.x;
    const long M4 = (1l << 20) / 4;
    float4 a = reinterpret_cast<const float4*>(Gw)[i4];
    float4 b = reinterpret_cast<const float4*>(Gw)[i4 + M4];
    float4 c = reinterpret_cast<const float4*>(Gw)[i4 + 2 * M4];
    float4 d = reinterpret_cast<const float4*>(Gw)[i4 + 3 * M4];
    float sx = (a.x + b.x + c.x + d.x) * 0.03125f;
    float sy = (a.y + b.y + c.y + d.y) * 0.03125f;
    float sz = (a.z + b.z + c.z + d.z) * 0.03125f;
    float sw = (a.w + b.w + c.w + d.w) * 0.03125f;
    uint2 o;
    o.x = (unsigned)f2bf(sx) | ((unsigned)f2bf(sy) << 16);
    o.y = (unsigned)f2bf(sz) | ((unsigned)f2bf(sw) << 16);
    reinterpret_cast<uint2*>(Gp)[i4] = o;
}

// ===================== PV ring pipeline (T3+T4 on K-32 subtiles) =====================
// Ring of 4 subtile slots (A 8KB + B 8KB each) = 64KB -> 2 blocks/CU. 3 subtiles in
// flight, counted vmcnt (12/8/4/0 at tail) — never drains mid-loop.
// Bank swizzle: piece ^= (row&3)^((row>>2)&3)  (16 lanes -> 8 banks = 2-way, free).
__device__ __forceinline__ void stage_sub(char* Aslot, char* Bslot,
                                          const unsigned short* A, int lda,
                                          const unsigned short* B, int ldb, int k0,
                                          int wid, int lane) {
    const int r  = lane >> 2;
    const int pg = (lane & 3) ^ (r & 3) ^ ((r >> 2) & 3);   // inverse-swizzled source piece
    #pragma unroll
    for (int i = 0; i < 2; ++i) {
        const int chunk = wid * 2 + i;             // 0..7 across 4 waves
        const int row = chunk * 16 + r;            // chunk*16 ≡ 0 mod 16 keeps swz row-bits = r-bits
        __builtin_amdgcn_global_load_lds(
            (gvp)(A + (long)row * lda + k0 + pg * 8),
            (lvp)(Aslot + chunk * 1024), 16, 0, 0);
        __builtin_amdgcn_global_load_lds(
            (gvp)(B + (long)row * ldb + k0 + pg * 8),
            (lvp)(Bslot + chunk * 1024), 16, 0, 0);
    }
}

__device__ __forceinline__ void compute_sub(floatx4 acc[4][4], const char* Asl,
                                            const char* Bsl, int wm, int wn,
                                            int frow, int lane) {
    short8 af[4], bf[4];
    const int cp = lane >> 4;                      // k-piece 0..3 (8 bf16 each)
    #pragma unroll
    for (int i = 0; i < 4; ++i) {
        const int ar = wm + i * 16 + frow;
        af[i] = *reinterpret_cast<const short8*>(
            Asl + ar * 64 + ((cp ^ (ar & 3) ^ ((ar >> 2) & 3)) << 4));
        const int br = wn + i * 16 + frow;
        bf[i] = *reinterpret_cast<const short8*>(
            Bsl + br * 64 + ((cp ^ (br & 3) ^ ((br >> 2) & 3)) << 4));
    }
    WAITL();
    __builtin_amdgcn_s_setprio(1);
    #pragma unroll
    for (int i = 0; i < 4; ++i)
        #pragma unroll
        for (int j = 0; j < 4; ++j)
            acc[i][j] = __builtin_amdgcn_mfma_f32_16x16x32_bf16(af[i], bf[j], acc[i][j], 0, 0, 0);
    __builtin_amdgcn_s_setprio(0);
}

__global__ __launch_bounds__(256, 2)
void pv_ring(const unsigned short* __restrict__ P, const unsigned short* __restrict__ Vt,
             float* __restrict__ out) {
    int flat = (blockIdx.z * 8 + blockIdx.y) * 8 + blockIdx.x;
    { int xcd = flat & 7, lid = flat >> 3; flat = xcd * 32 + lid; }
    const int bx = flat % 8;
    const int pj = (flat / 8) % 8;
    const int bz = flat / 64;

    const unsigned short* Pb = P + (long)bz * 2048 * 4096;   // bf16 view of f32 rows
    const unsigned short* Bv = Vt + (long)bz * 1024 * 2048 + (long)(bx * 128) * 2048;
    float* Cb = out + (long)bz * 2048 * 1024;

    __shared__ __align__(16) char ring[4][2][8192];          // [slot][A/B][128r x 32c bf16]

    const int tid = threadIdx.x, lane = tid & 63, wid = tid >> 6;
    const int wm = (wid >> 1) * 64, wn = (wid & 1) * 64, frow = lane & 15;

    #pragma unroll 1
    for (int j = 0; j < 2; ++j) {
        const int by = j ? 15 - pj : pj;
        const unsigned short* A = Pb + (long)by * 128 * 4096;
        const int NS = (by + 1) * 4;               // K-32 subtiles (>= 4)

        floatx4 acc[4][4] = {};
        stage_sub(ring[0][0], ring[0][1], A, 4096, Bv, 2048, 0,  wid, lane);
        stage_sub(ring[1][0], ring[1][1], A, 4096, Bv, 2048, 32, wid, lane);
        stage_sub(ring[2][0], ring[2][1], A, 4096, Bv, 2048, 64, wid, lane);

        #pragma unroll 1
        for (int p = 0; p < NS; ++p) {
            BAR();                                  // slot (p+3)&3 == (p-1)&3 now free
            if (p + 3 < NS)
                stage_sub(ring[(p + 3) & 3][0], ring[(p + 3) & 3][1],
                          A, 4096, Bv, 2048, (p + 3) * 32, wid, lane);
            const int rem = min(NS - 1, p + 3) - p; // outstanding newer subtiles after wait
            if (rem >= 3)      { WAITV12(); }
            else if (rem == 2) { WAITV8();  }
            else if (rem == 1) { WAITV4();  }
            else               { WAITV0();  }
            BAR();                                  // slot p complete across all waves
            compute_sub(acc, ring[p & 3][0], ring[p & 3][1], wm, wn, frow, lane);
        }

        float* Cj = Cb + (long)(by * 128) * 1024 + bx * 128;
        const int cr0 = wm + (lane >> 4) * 4;
        const int cc0 = wn + (lane & 15);
        #pragma unroll
        for (int i = 0; i < 4; ++i)
            #pragma unroll
            for (int jj = 0; jj < 4; ++jj)
                #pragma unroll
                for (int r = 0; r < 4; ++r)
                    Cj[(long)(cr0 + i * 16 + r) * 1024 + cc0 + jj * 16] = acc[i][jj][r];

        WAITV0();   // drain epilogue stores so job-2 vmcnt counts stay exact
        BAR();      // and no wave restages while another still reads the ring
    }
}

// ===================== 256x256 8-phase GEMM =====================
__device__ __forceinline__ void stage_half(char* slot, const unsigned short* src,
                                           int ld, int k0, int tid) {
    #pragma unroll
    for (int r = 0; r < 2; ++r) {
        const int c = r * 512 + tid;
        const int row = c >> 3;
        const int cs = ((c & 7) * 16) ^ ((row & 7) << 4);
        const char* g = reinterpret_cast<const char*>(src + (long)row * ld + k0) + cs;
        __builtin_amdgcn_global_load_lds((gvp)g,
            (lvp)(slot + r * 8192 + (tid >> 6) * 1024), 16, 0, 0);
    }
}

__device__ __forceinline__ void load_a4(short8 a_[4][2], const char* slot, int mh,
                                        int fr, int csw0, int csw1) {
    #pragma unroll
    for (int i = 0; i < 4; ++i) {
        const int rb = (mh * 64 + i * 16 + fr) * 128;
        a_[i][0] = *reinterpret_cast<const short8*>(slot + rb + csw0);
        a_[i][1] = *reinterpret_cast<const short8*>(slot + rb + csw1);
    }
}

__device__ __forceinline__ void load_b2(short8 b_[2][2], const char* slot, int rbase,
                                        int nh, int fr, int csw0, int csw1) {
    #pragma unroll
    for (int j = 0; j < 2; ++j) {
        const int rb = (rbase + nh * 32 + j * 16 + fr) * 128;
        b_[j][0] = *reinterpret_cast<const short8*>(slot + rb + csw0);
        b_[j][1] = *reinterpret_cast<const short8*>(slot + rb + csw1);
    }
}

__device__ __forceinline__ void mfma16(floatx4 acc[8][4], short8 a_[4][2],
                                       short8 b_[2][2], int mh, int nh) {
    __builtin_amdgcn_s_setprio(1);
    #pragma unroll
    for (int i = 0; i < 4; ++i)
        #pragma unroll
        for (int j = 0; j < 2; ++j) {
            acc[mh*4+i][nh*2+j] = __builtin_amdgcn_mfma_f32_16x16x32_bf16(
                a_[i][0], b_[j][0], acc[mh*4+i][nh*2+j], 0, 0, 0);
            acc[mh*4+i][nh*2+j] = __builtin_amdgcn_mfma_f32_16x16x32_bf16(
                a_[i][1], b_[j][1], acc[mh*4+i][nh*2+j], 0, 0, 0);
        }
    __builtin_amdgcn_s_setprio(0);
}

#define WAITV4G() asm volatile("s_waitcnt vmcnt(4)")

template<typename CT, int MODE>
__global__ __launch_bounds__(512, 2)
void gemm8p(const unsigned short* __restrict__ A, const unsigned short* B,
            const unsigned short* B1, CT* __restrict__ C, unsigned short* __restrict__ Vt,
            int K, int lda, int ldb, int ldc,
            long sA, long sB, long sC, int nwg)
{
    const int gx = gridDim.x, gy = gridDim.y;
    int flat = (blockIdx.z * gy + blockIdx.y) * gx + blockIdx.x;
    int bx, by, bz = 0;
    bool isV = false;
    if (MODE == 1) {
        int xcd = flat & 7, lid = flat >> 3;
        int q = nwg >> 3, r = nwg & 7;
        flat = (xcd < r ? xcd * (q + 1) : r * (q + 1) + (xcd - r) * q) + lid;
        bx = flat % gx;
        int t2 = flat / gx;
        by = t2 % gy;
        bz = t2 / gy;
        if (bx > by) return;
    } else {
        const int xcd = flat & 7, lid = flat >> 3;
        by = xcd + ((lid >> 3) << 3);
        const int sub = lid & 7;
        isV = (sub >> 2) != 0;
        bx = sub & 3;
        if (isV) B = B1;
    }

    A += (long)bz * sA + (long)by * 256 * lda;
    B += (long)bz * sB + (long)bx * 256 * ldb;
    C += (long)bz * sC;

    __shared__ __align__(16) char lds[8 * 16384];
    #define SLOT(db, op, half) (lds + ((((db) << 1 | (op)) << 1 | (half)) * 16384))

    const int tid  = threadIdx.x;
    const int lane = tid & 63;
    const int wid  = tid >> 6;
    const int wm = wid >> 2;
    const int wn = wid & 3;
    const int bh = wn >> 1;
    const int brbase = (wn & 1) * 64;
    const int fr = lane & 15;
    const int csw0 = ((lane >> 4) * 16) ^ ((fr & 7) << 4);
    const int csw1 = (64 + (lane >> 4) * 16) ^ ((fr & 7) << 4);

    const unsigned short* Ah[2] = { A, A + 128ll * lda };
    const unsigned short* Bh[2] = { B, B + 128ll * ldb };

    const int NT = K >> 6;
    const int NI = NT >> 1;

    floatx4 acc[8][4] = {};
    short8 a_[4][2];
    short8 b_[2][2][2];

    stage_half(SLOT(0,1,0), Bh[0], ldb, 0, tid);
    stage_half(SLOT(0,1,1), Bh[1], ldb, 0, tid);
    stage_half(SLOT(0,0,0), Ah[0], lda, 0, tid);
    stage_half(SLOT(0,0,1), Ah[1], lda, 0, tid);
    stage_half(SLOT(1,1,0), Bh[0], ldb, 64, tid);
    stage_half(SLOT(1,1,1), Bh[1], ldb, 64, tid);
    WAITV4G();
    BAR();

    for (int I = 0; I < NI; ++I) {
        const int kA1 = min(2*I + 1, NT - 1) * 64;
        const int kT2 = min(2*I + 2, NT - 1) * 64;
        const int kB3 = min(2*I + 3, NT - 1) * 64;

        load_a4(a_, SLOT(0,0,wm), 0, fr, csw0, csw1);
        load_b2(b_[0], SLOT(0,1,bh), brbase, 0, fr, csw0, csw1);
        stage_half(SLOT(1,0,0), Ah[0], lda, kA1, tid);
        BAR(); WAITL();
        mfma16(acc, a_, b_[0], 0, 0);
        BAR();

        load_b2(b_[1], SLOT(0,1,bh), brbase, 1, fr, csw0, csw1);
        stage_half(SLOT(1,0,1), Ah[1], lda, kA1, tid);
        BAR(); WAITL();
        mfma16(acc, a_, b_[1], 0, 1);
        BAR();

        load_a4(a_, SLOT(0,0,wm), 1, fr, csw0, csw1);
        stage_half(SLOT(0,1,0), Bh[0], ldb, kT2, tid);
        BAR(); WAITL();
        mfma16(acc, a_, b_[1], 1, 1);
        BAR();

        stage_half(SLOT(0,1,1), Bh[1], ldb, kT2, tid);
        BAR(); WAITL();
        mfma16(acc, a_, b_[0], 1, 0);
        WAITV4G();
        BAR();

        load_a4(a_, SLOT(1,0,wm), 0, fr, csw0, csw1);
        load_b2(b_[0], SLOT(1,1,bh), brbase, 0, fr, csw0, csw1);
        stage_half(SLOT(0,0,0), Ah[0], lda, kT2, tid);
        BAR(); WAITL();
        mfma16(acc, a_, b_[0], 0, 0);
        BAR();

        load_b2(b_[1], SLOT(1,1,bh), brbase, 1, fr, csw0, csw1);
        stage_half(SLOT(0,0,1), Ah[1], lda, kT2, tid);
        BAR(); WAITL();
        mfma16(acc, a_, b_[1], 0, 1);
        BAR();

        load_a4(a_, SLOT(1,0,wm), 1, fr, csw0, csw1);
        stage_half(SLOT(1,1,0), Bh[0], ldb, kB3, tid);
        BAR(); WAITL();
        mfma16(acc, a_, b_[1], 1, 1);
        BAR();

        stage_half(SLOT(1,1,1), Bh[1], ldb, kB3, tid);
        BAR(); WAITL();
        mfma16(acc, a_, b_[0], 1, 0);
        WAITV4G();
        BAR();
    }

    if (MODE == 3 && isV) {
        WAITV0();
        BAR();
        char* T = lds;
        #pragma unroll
        for (int i = 0; i < 8; ++i)
            #pragma unroll
            for (int j = 0; j < 4; ++j) {
                const int n = wn * 64 + j * 16 + fr;
                const int m = wm * 128 + ((lane >> 4) << 2) + i * 16;
                uint2 pk;
                pk.x = (unsigned)f2bf(acc[i][j][0]) | ((unsigned)f2bf(acc[i][j][1]) << 16);
                pk.y = (unsigned)f2bf(acc[i][j][2]) | ((unsigned)f2bf(acc[i][j][3]) << 16);
                *reinterpret_cast<uint2*>(T + n * 512 + ((m * 2) ^ ((n & 7) << 4))) = pk;
            }
        __syncthreads();
        const int b  = by >> 3;
        const int s0 = (by & 7) * 256;
        #pragma unroll
        for (int c = 0; c < 16; ++c) {
            const int idx = c * 512 + tid;
            const int n = idx >> 5, k = idx & 31;
            uint4 v = *reinterpret_cast<const uint4*>(T + n * 512 + ((k * 16) ^ ((n & 7) << 4)));
            *reinterpret_cast<uint4*>(Vt + (long)b * (1024 * 2048)
                + (long)(bx * 256 + n) * 2048 + s0 + k * 8) = v;
        }
        return;
    }

    const int cr0 = by * 256 + wm * 128 + (lane >> 4) * 4;
    const int cc0 = bx * 256 + wn * 64 + (lane & 15);
    #pragma unroll
    for (int i = 0; i < 8; ++i)
        #pragma unroll
        for (int j = 0; j < 4; ++j)
            #pragma unroll
            for (int r = 0; r < 4; ++r) {
                long idx = (long)(cr0 + i * 16 + r) * ldc + (cc0 + j * 16);
                float v = acc[i][j][r];
                if constexpr (sizeof(CT) == 4) C[idx] = v;
                else                           C[idx] = (CT)f2bf(v);
            }
    #undef SLOT
}

// ---------------- causal softmax, row-paired (q, 2047-q): uniform work ----------------
__global__ __launch_bounds__(256)
void softmax_causal(float* __restrict__ Sc) {
    const int b = blockIdx.y;
    const int t = threadIdx.x;
    const int lane = t & 63, wid = t >> 6;
    __shared__ float rmax[2][4], rsum[2][4];

    #pragma unroll 1
    for (int h = 0; h < 2; ++h) {
        const int q = h ? 2047 - blockIdx.x : blockIdx.x;
        float* row = Sc + ((long)b * 2048 + q) * 2048;
        const int kend = (q | 127) + 1;

        float vals[8];
        float mx = -INFINITY;
        #pragma unroll
        for (int i = 0; i < 2; ++i) {
            const int c0 = i * 1024 + t * 4;
            if (c0 <= q) {
                float4 v = *reinterpret_cast<const float4*>(row + c0);
                float tmp[4] = {v.x, v.y, v.z, v.w};
                #pragma unroll
                for (int j = 0; j < 4; ++j) {
                    float val = (c0 + j <= q) ? tmp[j] : -INFINITY;
                    vals[i * 4 + j] = val;
                    mx = fmaxf(mx, val);
                }
            } else {
                vals[i*4+0] = vals[i*4+1] = vals[i*4+2] = vals[i*4+3] = -INFINITY;
            }
        }
        #pragma unroll
        for (int o = 32; o > 0; o >>= 1) mx = fmaxf(mx, __shfl_xor(mx, o));
        if (lane == 0) rmax[h][wid] = mx;
        __syncthreads();
        mx = fmaxf(fmaxf(rmax[h][0], rmax[h][1]), fmaxf(rmax[h][2], rmax[h][3]));

        float s = 0.f;
        #pragma unroll
        for (int k = 0; k < 8; ++k) {
            float e = __expf(vals[k] - mx);
            vals[k] = e;
            s += e;
        }
        #pragma unroll
        for (int o = 32; o > 0; o >>= 1) s += __shfl_xor(s, o);
        if (lane == 0) rsum[h][wid] = s;
        __syncthreads();
        s = rsum[h][0] + rsum[h][1] + rsum[h][2] + rsum[h][3];
        const float inv = 1.f / s;

        unsigned short* orow = reinterpret_cast<unsigned short*>(row);
        #pragma unroll
        for (int i = 0; i < 2; ++i) {
            const int c0 = i * 1024 + t * 4;
            if (c0 < kend) {
                uint2 o;
                o.x = (unsigned)f2bf(vals[i*4+0] * inv) | ((unsigned)f2bf(vals[i*4+1] * inv) << 16);
                o.y = (unsigned)f2bf(vals[i*4+2] * inv) | ((unsigned)f2bf(vals[i*4+3] * inv) << 16);
                *reinterpret_cast<uint2*>(orow + c0) = o;
            }
        }
    }
}

extern "C" void kernel_launch(void* const* d_in, const int* in_sizes, int n_in,
                              void* d_out, int out_size, void* d_ws, size_t ws_size,
                              hipStream_t stream) {
    const float* x  = (const float*)d_in[0];
    const float* Wq = (const float*)d_in[1];
    const float* Wk = (const float*)d_in[2];
    const float* Wv = (const float*)d_in[3];
    float* out = (float*)d_out;

    char* w = (char*)d_ws;
    unsigned short* Xb  = (unsigned short*)(w);
    unsigned short* WqT = (unsigned short*)(w + (16ll << 20));
    unsigned short* WkT = (unsigned short*)(w + (18ll << 20));
    unsigned short* Wvb = (unsigned short*)(w + (20ll << 20));
    unsigned short* Yb  = (unsigned short*)(w + (22ll << 20));
    unsigned short* Gp  = (unsigned short*)(w + (38ll << 20));
    float*          Gw  = (float*)(w + (40ll << 20));
    unsigned short* Vt  = (unsigned short*)(w + (70ll << 20));
    float* Sc = (float*)(w + (86ll << 20));

    dim3 blk(256);
    cvt_all<<<2816, blk, 0, stream>>>(x, Wq, Wk, Wv, Xb, WqT, WkT, Wvb);

    g_chunk<<<dim3(8, 8, 4), blk, 0, stream>>>(WkT, WqT, Gw);
    reduce_g<<<1024, blk, 0, stream>>>(Gw, Gp);

    gemm8p<unsigned short, 3><<<dim3(256, 1, 1), dim3(512), 0, stream>>>(
        Xb, Gp, Wvb, Yb, Vt, 1024, 1024, 1024, 1024,
        0, 0, 0, 256);

    gemm8p<float, 1><<<dim3(8, 8, 4), dim3(512), 0, stream>>>(
        Yb, Xb, nullptr, Sc, nullptr, 1024, 1024, 1024, 2048,
        2048ll * 1024, 2048ll * 1024, 2048ll * 2048, 256);

    softmax_causal<<<dim3(1024, 4), blk, 0, stream>>>(Sc);

    // out = P @ V  (ring-pipelined counted-vmcnt, complementary pairing)
    pv_ring<<<dim3(8, 8, 4), blk, 0, stream>>>((const unsigned short*)Sc, Vt, out);
}